// Round 17
// baseline (516.901 us; speedup 1.0000x reference)
//
#include <hip/hip_runtime.h>
#include <hip/hip_bf16.h>

// CrossAttention: B=4, Tv=8192, Tt=77, C=1024, H=16, D=64
// Round 16: fuse video fp32->bf16 into q-GEMM A-staging via reg-pipeline
// (same 8-phase schedule; A staged by reg-load + cvt + ds_write in stage_h's slots;
// B unchanged via global_load_lds + counted vmcnt). Video-cvt pass removed from prep.

typedef __attribute__((ext_vector_type(8))) short bf16x8;
typedef __attribute__((ext_vector_type(4))) float f32x4;
typedef __attribute__((ext_vector_type(8))) unsigned short u16x8;
typedef __attribute__((ext_vector_type(4))) unsigned short u16x4;

typedef const __attribute__((address_space(1))) void gv_t;
typedef __attribute__((address_space(3))) void lv_t;

static __device__ __forceinline__ unsigned short f2bf(float f) {
    union { float f; unsigned u; } v; v.f = f;
    unsigned r = v.u + 0x7FFFu + ((v.u >> 16) & 1u);  // RNE
    return (unsigned short)(r >> 16);
}

constexpr int Bn = 4, TVn = 8192, TTn = 77, Cn = 1024, Hn = 16;

// ---------------- merged prep: kv-gemm (48 blocks, pipelined) + Wq/Wo cvt ----------------
__device__ __forceinline__ void cvt8_body(const float* __restrict__ in,
                                          unsigned short* __restrict__ out, int i) {
    const float4* p = reinterpret_cast<const float4*>(in) + (size_t)i * 2;
    float4 a = p[0], b = p[1];
    u16x8 o = { f2bf(a.x), f2bf(a.y), f2bf(a.z), f2bf(a.w),
                f2bf(b.x), f2bf(b.y), f2bf(b.z), f2bf(b.w) };
    *reinterpret_cast<u16x8*>(out + (size_t)i * 8) = o;
}

__global__ __launch_bounds__(256)
void k_prep(const float* __restrict__ text,
            const float* __restrict__ Wq, const float* __restrict__ Wk,
            const float* __restrict__ Wv, const float* __restrict__ Wo,
            unsigned short* __restrict__ wq_b, unsigned short* __restrict__ wo_b,
            unsigned short* __restrict__ kbuf, unsigned short* __restrict__ vbuf) {
    __shared__ unsigned short As[128 * 32];
    __shared__ unsigned short Bs[128 * 32];
    const int tid = threadIdx.x;
    int bid = blockIdx.x;

    if (bid >= 48) {                                   // weight conversion blocks
        bid -= 48;
        if (bid < 512) cvt8_body(Wq, wq_b, bid * 256 + tid);
        else           cvt8_body(Wo, wo_b, (bid - 512) * 256 + tid);
        return;
    }
    // ---- kv projection: text fp32 [308][1024] @ W^T -> bf16, reg-double-buffered (R15 proven)
    const int bx = bid % 3, by = (bid / 3) % 8, bz = bid / 24;
    const float* W = bz ? Wv : Wk;
    unsigned short* out = bz ? vbuf : kbuf;
    const int M = Bn * TTn;
    const int lane = tid & 63, wv = tid >> 6;
    const int m0 = bx * 128, n0 = by * 128;
    const int wr = (wv >> 1) * 64, wc = (wv & 1) * 64;
    const int lr = lane & 15, lk = (lane >> 4) * 8, lg = lane >> 4;
    const int srow = tid >> 3, sc4 = (tid & 7) * 4;
    f32x4 acc[4][4] = {};

    float4 a0[4], b0[4], a1[4], b1[4];

#define KV_LOAD(kk, ra, rb)                                                            \
    {                                                                                  \
        _Pragma("unroll")                                                              \
        for (int it = 0; it < 4; ++it) {                                               \
            int row = it * 32 + srow;                                                  \
            int gr = m0 + row;                                                         \
            ra[it] = make_float4(0.f, 0.f, 0.f, 0.f);                                  \
            if (gr < M) ra[it] = *reinterpret_cast<const float4*>(                     \
                text + (size_t)gr * 1024 + (kk) + sc4);                                \
            rb[it] = *reinterpret_cast<const float4*>(                                 \
                W + (size_t)(n0 + row) * 1024 + (kk) + sc4);                           \
        }                                                                              \
    }

#define KV_WRITE(ra, rb)                                                               \
    {                                                                                  \
        _Pragma("unroll")                                                              \
        for (int it = 0; it < 4; ++it) {                                               \
            int row = it * 32 + srow;                                                  \
            u16x4 oa = { f2bf(ra[it].x), f2bf(ra[it].y), f2bf(ra[it].z), f2bf(ra[it].w) }; \
            *reinterpret_cast<u16x4*>(&As[row * 32 + sc4]) = oa;                       \
            u16x4 ob = { f2bf(rb[it].x), f2bf(rb[it].y), f2bf(rb[it].z), f2bf(rb[it].w) }; \
            *reinterpret_cast<u16x4*>(&Bs[row * 32 + sc4]) = ob;                       \
        }                                                                              \
    }

#define KV_COMPUTE()                                                                   \
    {                                                                                  \
        bf16x8 af[4], bfv[4];                                                          \
        _Pragma("unroll")                                                              \
        for (int m = 0; m < 4; ++m)                                                    \
            af[m] = *reinterpret_cast<const bf16x8*>(&As[(wr + m * 16 + lr) * 32 + lk]); \
        _Pragma("unroll")                                                              \
        for (int n = 0; n < 4; ++n)                                                    \
            bfv[n] = *reinterpret_cast<const bf16x8*>(&Bs[(wc + n * 16 + lr) * 32 + lk]); \
        _Pragma("unroll")                                                              \
        for (int m = 0; m < 4; ++m)                                                    \
            _Pragma("unroll")                                                          \
            for (int n = 0; n < 4; ++n)                                                \
                acc[m][n] = __builtin_amdgcn_mfma_f32_16x16x32_bf16(af[m], bfv[n], acc[m][n], 0, 0, 0); \
    }

    KV_LOAD(0, a0, b0);
    for (int kk = 0; kk < 1024; kk += 64) {
        __syncthreads();
        KV_WRITE(a0, b0);
        if (kk + 32 < 1024) KV_LOAD(kk + 32, a1, b1);
        __syncthreads();
        KV_COMPUTE();
        __syncthreads();
        KV_WRITE(a1, b1);
        if (kk + 64 < 1024) KV_LOAD(kk + 64, a0, b0);
        __syncthreads();
        KV_COMPUTE();
    }
#undef KV_LOAD
#undef KV_WRITE
#undef KV_COMPUTE

    #pragma unroll
    for (int m = 0; m < 4; ++m)
        #pragma unroll
        for (int n = 0; n < 4; ++n)
            #pragma unroll
            for (int r = 0; r < 4; ++r) {
                int grow = m0 + wr + m * 16 + lg * 4 + r;
                if (grow < M) {
                    int gcol = n0 + wc + n * 16 + lr;
                    out[(size_t)grow * 1024 + gcol] = f2bf(acc[m][n][r]);
                }
            }
}

// ================= shared GEMM pieces =================
__device__ __forceinline__ void stage_h(const unsigned short* __restrict__ src, int grow0, int kcol0,
                                        unsigned short* lds, int tid) {
    #pragma unroll
    for (int j = 0; j < 2; ++j) {
        const int row = j * 64 + (tid >> 3);
        const int sseg = (tid & 7) ^ (row & 7);
        const unsigned short* g = src + (size_t)(grow0 + row) * 1024 + kcol0 + sseg * 8;
        unsigned short* d = lds + j * 4096 + (tid >> 6) * 512;
        __builtin_amdgcn_global_load_lds((gv_t*)g, (lv_t*)d, 16, 0, 0);
    }
}

template<int BUF, int MQ>
__device__ __forceinline__ void p8_loadA(bf16x8 (&af)[4][2],
        const unsigned short (&As)[2][2][128][64], int wm, int lr, int lg) {
    #pragma unroll
    for (int m4 = 0; m4 < 4; ++m4)
        #pragma unroll
        for (int kk = 0; kk < 2; ++kk) {
            const int rl = MQ * 64 + m4 * 16 + lr;
            af[m4][kk] = *reinterpret_cast<const bf16x8*>(
                &As[BUF][wm][rl][((kk * 4 + lg) ^ (rl & 7)) * 8]);
        }
}

template<int BUF, int NQ>
__device__ __forceinline__ void p8_loadB(bf16x8 (&bg)[2][2],
        const unsigned short (&Bs)[2][2][128][64], int wn, int lr, int lg) {
    #pragma unroll
    for (int n2 = 0; n2 < 2; ++n2)
        #pragma unroll
        for (int kk = 0; kk < 2; ++kk) {
            const int nrow = wn * 64 + (NQ * 2 + n2) * 16 + lr;
            bg[n2][kk] = *reinterpret_cast<const bf16x8*>(
                &Bs[BUF][nrow >> 7][nrow & 127][((kk * 4 + lg) ^ (nrow & 7)) * 8]);
        }
}

template<int MQ, int NQ>
__device__ __forceinline__ void p8_mfma(f32x4 (&acc)[8][4],
        const bf16x8 (&af)[4][2], const bf16x8 (&bg)[2][2]) {
    #pragma unroll
    for (int m4 = 0; m4 < 4; ++m4)
        #pragma unroll
        for (int n2 = 0; n2 < 2; ++n2)
            #pragma unroll
            for (int kk = 0; kk < 2; ++kk)
                acc[MQ * 4 + m4][NQ * 2 + n2] = __builtin_amdgcn_mfma_f32_16x16x32_bf16(
                    af[m4][kk], bg[n2][kk], acc[MQ * 4 + m4][NQ * 2 + n2], 0, 0, 0);
}

#define P8_PRE()                                              \
    __builtin_amdgcn_s_barrier();                             \
    __builtin_amdgcn_s_setprio(1);

// ================= fused q-GEMM: video fp32 @ Wq^T -> qh head-major =================
// A staged via reg-load(t+2 at P0 / t+3 at P4) + cvt + ds_write in stage_h's exact slots.
__global__ __launch_bounds__(512, 1)
void k_gq_fused(const float* __restrict__ A, const unsigned short* __restrict__ Wb,
                unsigned short* __restrict__ outp) {
    __shared__ unsigned short As[2][2][128][64];   // 64 KiB
    __shared__ unsigned short Bs[2][2][128][64];   // 64 KiB
    const int tid = threadIdx.x, lane = tid & 63;
    const int wid = tid >> 6, wm = wid >> 2, wn = wid & 3;
    const int orig = blockIdx.x;
    const int work = (orig & 7) * 64 + (orig >> 3);
    const int m0 = (work >> 2) * 256, n0 = (work & 3) * 256;
    const int lr = lane & 15, lg = lane >> 4;
    const int srow = tid >> 3, sw = tid & 7, sa = (tid & 7) ^ ((tid >> 3) & 7);

    f32x4 acc[8][4] = {};
    bf16x8 af[4][2], bg0[2][2], bg1[2][2];
    float4 ra0[2][2][2], ra1[2][2][2];   // [half][j][2] two named banks, static indexing

#define AQ_LOAD(bank, kt)                                                          \
    { const int kc_ = (kt) * 64;                                                   \
      _Pragma("unroll") for (int hh = 0; hh < 2; ++hh)                             \
      _Pragma("unroll") for (int j = 0; j < 2; ++j) {                              \
          const float* g_ = A + (size_t)(m0 + hh * 128 + j * 64 + srow) * 1024 + kc_ + sa * 8; \
          bank[hh][j][0] = *reinterpret_cast<const float4*>(g_);                   \
          bank[hh][j][1] = *reinterpret_cast<const float4*>(g_ + 4);               \
      } }

#define AQ_WRITE(bank, BUF, HH)                                                    \
    { _Pragma("unroll") for (int j = 0; j < 2; ++j) {                              \
          float4 u_ = bank[HH][j][0], v_ = bank[HH][j][1];                         \
          u16x8 o_ = { f2bf(u_.x), f2bf(u_.y), f2bf(u_.z), f2bf(u_.w),             \
                       f2bf(v_.x), f2bf(v_.y), f2bf(v_.z), f2bf(v_.w) };           \
          *reinterpret_cast<u16x8*>(&As[BUF][HH][j * 64 + srow][sw * 8]) = o_;     \
      } }

    // prologue: reg-load A(0),A(1); B(0)/B(1) via gload_lds; write A(0) into buf0
    AQ_LOAD(ra0, 0);
    AQ_LOAD(ra1, 1);
    stage_h(Wb, n0,       0,  &Bs[0][0][0][0], tid);
    stage_h(Wb, n0 + 128, 0,  &Bs[0][1][0][0], tid);
    stage_h(Wb, n0,       64, &Bs[1][0][0][0], tid);
    stage_h(Wb, n0 + 128, 64, &Bs[1][1][0][0], tid);
    AQ_WRITE(ra0, 0, 0);
    AQ_WRITE(ra0, 0, 1);
    asm volatile("s_waitcnt vmcnt(4)" ::: "memory");   // B(0) landed; B(1) in flight
    asm volatile("s_waitcnt lgkmcnt(0)" ::: "memory"); // A(0) ds_writes visible
    __builtin_amdgcn_s_barrier();

    for (int t = 0; t < 16; t += 2) {
        const int k1 = (t + 1) * 64;
        const bool s2 = (t + 2) < 16, s3 = (t + 3) < 16;
        // P0: tile t (mq0,nq0); write A(t+1)-half0 from ra1; load A(t+2) -> ra0
        p8_loadA<0, 0>(af, As, wm, lr, lg);
        p8_loadB<0, 0>(bg0, Bs, wn, lr, lg);
        AQ_WRITE(ra1, 1, 0);
        if (s2) AQ_LOAD(ra0, t + 2);
        P8_PRE(); p8_mfma<0, 0>(acc, af, bg0);
        __builtin_amdgcn_s_setprio(0); __builtin_amdgcn_s_barrier();
        // P1: (mq0,nq1); write A(t+1)-half1
        p8_loadB<0, 1>(bg1, Bs, wn, lr, lg);
        AQ_WRITE(ra1, 1, 1);
        P8_PRE(); p8_mfma<0, 1>(acc, af, bg1);
        __builtin_amdgcn_s_setprio(0);
        asm volatile("s_waitcnt lgkmcnt(0)" ::: "memory");  // A(t+1) writes visible
        __builtin_amdgcn_s_barrier();
        // P2: (mq1,nq1); stage B0(t+2)
        p8_loadA<0, 1>(af, As, wm, lr, lg);
        if (s2) stage_h(Wb, n0, k1 + 64, &Bs[0][0][0][0], tid);
        P8_PRE(); p8_mfma<1, 1>(acc, af, bg1);
        __builtin_amdgcn_s_setprio(0); __builtin_amdgcn_s_barrier();
        // P3: (mq1,nq0); stage B1(t+2); counted vmcnt (drains ra0 loads + older B)
        if (s2) stage_h(Wb, n0 + 128, k1 + 64, &Bs[0][1][0][0], tid);
        P8_PRE(); p8_mfma<1, 0>(acc, af, bg0);
        __builtin_amdgcn_s_setprio(0);
        if (s2) { asm volatile("s_waitcnt vmcnt(4)" ::: "memory"); }
        else    { asm volatile("s_waitcnt vmcnt(0)" ::: "memory"); }
        __builtin_amdgcn_s_barrier();
        // P4: tile t+1 (mq0,nq0); write A(t+2)-half0 from ra0; load A(t+3) -> ra1
        p8_loadA<1, 0>(af, As, wm, lr, lg);
        p8_loadB<1, 0>(bg0, Bs, wn, lr, lg);
        if (s2) AQ_WRITE(ra0, 0, 0);
        if (s3) AQ_LOAD(ra1, t + 3);
        P8_PRE(); p8_mfma<0, 0>(acc, af, bg0);
        __builtin_amdgcn_s_setprio(0); __builtin_amdgcn_s_barrier();
        // P5: (mq0,nq1); write A(t+2)-half1
        p8_loadB<1, 1>(bg1, Bs, wn, lr, lg);
        if (s2) AQ_WRITE(ra0, 0, 1);
        P8_PRE(); p8_mfma<0, 1>(acc, af, bg1);
        __builtin_amdgcn_s_setprio(0);
        asm volatile("s_waitcnt lgkmcnt(0)" ::: "memory");  // A(t+2) writes visible
        __builtin_amdgcn_s_barrier();
        // P6: (mq1,nq1); stage B0(t+3)
        p8_loadA<1, 1>(af, As, wm, lr, lg);
        if (s3) stage_h(Wb, n0, k1 + 128, &Bs[1][0][0][0], tid);
        P8_PRE(); p8_mfma<1, 1>(acc, af, bg1);
        __builtin_amdgcn_s_setprio(0); __builtin_amdgcn_s_barrier();
        // P7: (mq1,nq0); stage B1(t+3); counted vmcnt (drains ra1 loads + older B)
        if (s3) stage_h(Wb, n0 + 128, k1 + 128, &Bs[1][1][0][0], tid);
        P8_PRE(); p8_mfma<1, 0>(acc, af, bg0);
        __builtin_amdgcn_s_setprio(0);
        if (s3) { asm volatile("s_waitcnt vmcnt(4)" ::: "memory"); }
        else    { asm volatile("s_waitcnt vmcnt(0)" ::: "memory"); }
        __builtin_amdgcn_s_barrier();
    }
#undef AQ_LOAD
#undef AQ_WRITE

    // head-major epilogue: qh[h][grow][d]
    #pragma unroll
    for (int mf = 0; mf < 8; ++mf)
        #pragma unroll
        for (int nf = 0; nf < 4; ++nf)
            #pragma unroll
            for (int r = 0; r < 4; ++r) {
                int grow = m0 + wm * 128 + mf * 16 + lg * 4 + r;
                int gcol = n0 + wn * 64 + nf * 16 + lr;
                unsigned short bv = f2bf(acc[mf][nf][r]);
                unsigned ov = __shfl_xor((unsigned)bv, 1);
                if (!(lane & 1)) {
                    size_t off = ((size_t)(gcol >> 6) * (Bn * TVn) + grow) * 64 + (gcol & 63);
                    *reinterpret_cast<unsigned*>(outp + off) = (unsigned)bv | (ov << 16);
                }
            }
}

// ================= 256x256 8-phase GEMM (o-proj, fp32 out) — R15 proven =================
template<int OUT_MODE>
__global__ __launch_bounds__(512, 1)
void k_g256p8(const unsigned short* __restrict__ A, const unsigned short* __restrict__ Wb,
              void* __restrict__ outp) {
    __shared__ unsigned short As[2][2][128][64];
    __shared__ unsigned short Bs[2][2][128][64];
    const int tid = threadIdx.x, lane = tid & 63;
    const int wid = tid >> 6, wm = wid >> 2, wn = wid & 3;
    const int orig = blockIdx.x;
    const int work = (orig & 7) * 64 + (orig >> 3);
    const int m0 = (work >> 2) * 256, n0 = (work & 3) * 256;
    const int lr = lane & 15, lg = lane >> 4;

    f32x4 acc[8][4] = {};
    bf16x8 af[4][2], bg0[2][2], bg1[2][2];

    stage_h(A,  m0,       0,  &As[0][0][0][0], tid);
    stage_h(A,  m0 + 128, 0,  &As[0][1][0][0], tid);
    stage_h(Wb, n0,       0,  &Bs[0][0][0][0], tid);
    stage_h(Wb, n0 + 128, 0,  &Bs[0][1][0][0], tid);
    stage_h(Wb, n0,       64, &Bs[1][0][0][0], tid);
    stage_h(Wb, n0 + 128, 64, &Bs[1][1][0][0], tid);
    asm volatile("s_waitcnt vmcnt(4)" ::: "memory");
    __builtin_amdgcn_s_barrier();

    for (int t = 0; t < 16; t += 2) {
        const int k1 = (t + 1) * 64;
        const bool s2 = (t + 2) < 16, s3 = (t + 3) < 16;
        p8_loadA<0, 0>(af, As, wm, lr, lg);
        p8_loadB<0, 0>(bg0, Bs, wn, lr, lg);
        stage_h(A, m0, k1, &As[1][0][0][0], tid);
        P8_PRE(); p8_mfma<0, 0>(acc, af, bg0);
        __builtin_amdgcn_s_setprio(0); __builtin_amdgcn_s_barrier();
        p8_loadB<0, 1>(bg1, Bs, wn, lr, lg);
        stage_h(A, m0 + 128, k1, &As[1][1][0][0], tid);
        P8_PRE(); p8_mfma<0, 1>(acc, af, bg1);
        __builtin_amdgcn_s_setprio(0); __builtin_amdgcn_s_barrier();
        p8_loadA<0, 1>(af, As, wm, lr, lg);
        if (s2) stage_h(Wb, n0, k1 + 64, &Bs[0][0][0][0], tid);
        P8_PRE(); p8_mfma<1, 1>(acc, af, bg1);
        __builtin_amdgcn_s_setprio(0); __builtin_amdgcn_s_barrier();
        if (s2) stage_h(Wb, n0 + 128, k1 + 64, &Bs[0][1][0][0], tid);
        P8_PRE(); p8_mfma<1, 0>(acc, af, bg0);
        __builtin_amdgcn_s_setprio(0);
        if (s2) { asm volatile("s_waitcnt vmcnt(4)" ::: "memory"); }
        else    { asm volatile("s_waitcnt vmcnt(0)" ::: "memory"); }
        __builtin_amdgcn_s_barrier();
        p8_loadA<1, 0>(af, As, wm, lr, lg);
        p8_loadB<1, 0>(bg0, Bs, wn, lr, lg);
        if (s2) stage_h(A, m0, k1 + 64, &As[0][0][0][0], tid);
        P8_PRE(); p8_mfma<0, 0>(acc, af, bg0);
        __builtin_amdgcn_s_setprio(0); __builtin_amdgcn_s_barrier();
        p8_loadB<1, 1>(bg1, Bs, wn, lr, lg);
        if (s2) stage_h(A, m0 + 128, k1 + 64, &As[0][1][0][0], tid);
        P8_PRE(); p8_mfma<0, 1>(acc, af, bg1);
        __builtin_amdgcn_s_setprio(0); __builtin_amdgcn_s_barrier();
        p8_loadA<1, 1>(af, As, wm, lr, lg);
        if (s3) stage_h(Wb, n0, k1 + 128, &Bs[1][0][0][0], tid);
        P8_PRE(); p8_mfma<1, 1>(acc, af, bg1);
        __builtin_amdgcn_s_setprio(0); __builtin_amdgcn_s_barrier();
        if (s3) stage_h(Wb, n0 + 128, k1 + 128, &Bs[1][1][0][0], tid);
        P8_PRE(); p8_mfma<1, 0>(acc, af, bg0);
        __builtin_amdgcn_s_setprio(0);
        if (s3) { asm volatile("s_waitcnt vmcnt(4)" ::: "memory"); }
        else    { asm volatile("s_waitcnt vmcnt(0)" ::: "memory"); }
        __builtin_amdgcn_s_barrier();
    }

    #pragma unroll
    for (int mf = 0; mf < 8; ++mf)
        #pragma unroll
        for (int nf = 0; nf < 4; ++nf)
            #pragma unroll
            for (int r = 0; r < 4; ++r) {
                int grow = m0 + wm * 128 + mf * 16 + lg * 4 + r;
                int gcol = n0 + wn * 64 + nf * 16 + lr;
                if (OUT_MODE == 0) {
                    float v = acc[mf][nf][r];
                    float o = __shfl_xor(v, 1);
                    if (!(lane & 1)) {
                        float* out = (float*)outp;
                        float2 pv; pv.x = v; pv.y = o;
                        *reinterpret_cast<float2*>(out + (size_t)grow * 1024 + gcol) = pv;
                    }
                } else {
                    unsigned short bv = f2bf(acc[mf][nf][r]);
                    unsigned ov = __shfl_xor((unsigned)bv, 1);
                    if (!(lane & 1)) {
                        unsigned short* out = (unsigned short*)outp;
                        size_t off = (OUT_MODE == 1)
                            ? (size_t)grow * 1024 + gcol
                            : ((size_t)(gcol >> 6) * (Bn * TVn) + grow) * 64 + (gcol & 63);
                        *reinterpret_cast<unsigned*>(out + off) = (unsigned)bv | (ov << 16);
                    }
                }
            }
}

// ---------------- attention v5 (R15 proven) ----------------
__global__ __launch_bounds__(512)
void k_attn5(const unsigned short* __restrict__ qh,
             const unsigned short* __restrict__ kb,
             const unsigned short* __restrict__ vb,
             unsigned short* __restrict__ aout) {
    constexpr int VP = 104;
    __shared__ unsigned short vt_s[64 * VP];
    const int tid = threadIdx.x, lane = tid & 63, wv = tid >> 6;
    const int m0 = blockIdx.x * 256;
    const int h = blockIdx.y, b = blockIdx.z;
    const size_t qhbase = ((size_t)h * (Bn * TVn) + (size_t)b * TVn + m0) * 64;
    const size_t kvbase = (size_t)b * TTn * Cn + h * 64;
    const int lr = lane & 15, lg = lane >> 4;

    for (int li = tid; li < 640; li += 512) {
        int t = li >> 3, sg = li & 7;
        u16x8 v = {0, 0, 0, 0, 0, 0, 0, 0};
        if (t < 77) v = *reinterpret_cast<const u16x8*>(vb + kvbase + (size_t)t * Cn + sg * 8);
        #pragma unroll
        for (int i = 0; i < 8; ++i) vt_s[(sg * 8 + i) * VP + t] = v[i];
    }
    for (int li = tid; li < 1024; li += 512) {
        int d = li >> 4, t = 80 + (li & 15);
        vt_s[d * VP + t] = 0;
    }

    f32x4 sc[2][5] = {};
    #pragma unroll
    for (int ks = 0; ks < 2; ++ks) {
        bf16x8 qa[2], kf[5];
        #pragma unroll
        for (int mf = 0; mf < 2; ++mf)
            qa[mf] = *reinterpret_cast<const bf16x8*>(
                qh + qhbase + (size_t)(wv * 32 + mf * 16 + lr) * 64 + ks * 32 + lg * 8);
        #pragma unroll
        for (int nf = 0; nf < 5; ++nf) {
            int t = nf * 16 + lr; if (t > 76) t = 76;
            kf[nf] = *reinterpret_cast<const bf16x8*>(
                kb + kvbase + (size_t)t * Cn + ks * 32 + lg * 8);
        }
        #pragma unroll
        for (int mf = 0; mf < 2; ++mf)
            #pragma unroll
            for (int nf = 0; nf < 5; ++nf)
                sc[mf][nf] = __builtin_amdgcn_mfma_f32_16x16x32_bf16(kf[nf], qa[mf], sc[mf][nf], 0, 0, 0);
    }

    unsigned pk[2][6][2];
    constexpr float CEXP = 0.125f * 1.44269504088896340736f;
    #pragma unroll
    for (int mf = 0; mf < 2; ++mf) {
        float mx = -1e30f;
        #pragma unroll
        for (int nf = 0; nf < 5; ++nf)
            #pragma unroll
            for (int r = 0; r < 4; ++r)
                if (!(nf == 4 && r >= 1)) mx = fmaxf(mx, sc[mf][nf][r]);
                else if (lg != 3)         mx = fmaxf(mx, sc[mf][nf][r]);
        mx = fmaxf(mx, __shfl_xor(mx, 16));
        mx = fmaxf(mx, __shfl_xor(mx, 32));
        float p[5][4];
        float sum = 0.f;
        #pragma unroll
        for (int nf = 0; nf < 5; ++nf)
            #pragma unroll
            for (int r = 0; r < 4; ++r) {
                bool valid = !(nf == 4 && lg == 3 && r >= 1);
                float pv = valid ? exp2f((sc[mf][nf][r] - mx) * CEXP) : 0.f;
                p[nf][r] = pv;
                sum += pv;
            }
        sum += __shfl_xor(sum, 16);
        sum += __shfl_xor(sum, 32);
        float inv = 1.f / sum;
        #pragma unroll
        for (int nf = 0; nf < 5; ++nf) {
            pk[mf][nf][0] = (unsigned)f2bf(p[nf][0] * inv) | ((unsigned)f2bf(p[nf][1] * inv) << 16);
            pk[mf][nf][1] = (unsigned)f2bf(p[nf][2] * inv) | ((unsigned)f2bf(p[nf][3] * inv) << 16);
        }
        pk[mf][5][0] = 0; pk[mf][5][1] = 0;
    }

    __syncthreads();

    f32x4 ovv[2][4] = {};
    const int sel = lg >> 1;
    const int srcA = ((lg & 1) * 2) * 16 + lr;
    const int srcB = ((lg & 1) * 2 + 1) * 16 + lr;
    #pragma unroll
    for (int ks = 0; ks < 3; ++ks) {
        bf16x8 vf[4];
        #pragma unroll
        for (int nf = 0; nf < 4; ++nf)
            vf[nf] = *reinterpret_cast<const bf16x8*>(
                &vt_s[(nf * 16 + lr) * VP + ks * 32 + lg * 8]);
        #pragma unroll
        for (int mf = 0; mf < 2; ++mf) {
            unsigned w0l = __shfl(pk[mf][ks * 2 + 0][0], srcA);
            unsigned w0h = __shfl(pk[mf][ks * 2 + 1][0], srcA);
            unsigned w1l = __shfl(pk[mf][ks * 2 + 0][1], srcA);
            unsigned w1h = __shfl(pk[mf][ks * 2 + 1][1], srcA);
            unsigned w2l = __shfl(pk[mf][ks * 2 + 0][0], srcB);
            unsigned w2h = __shfl(pk[mf][ks * 2 + 1][0], srcB);
            unsigned w3l = __shfl(pk[mf][ks * 2 + 0][1], srcB);
            unsigned w3h = __shfl(pk[mf][ks * 2 + 1][1], srcB);
            union { uint4 u; bf16x8 v; } pa;
            pa.u.x = sel ? w0h : w0l;
            pa.u.y = sel ? w1h : w1l;
            pa.u.z = sel ? w2h : w2l;
            pa.u.w = sel ? w3h : w3l;
            #pragma unroll
            for (int nf = 0; nf < 4; ++nf)
                ovv[mf][nf] = __builtin_amdgcn_mfma_f32_16x16x32_bf16(pa.v, vf[nf], ovv[mf][nf], 0, 0, 0);
        }
    }

    #pragma unroll
    for (int mf = 0; mf < 2; ++mf)
        #pragma unroll
        for (int nf = 0; nf < 4; ++nf)
            #pragma unroll
            for (int r = 0; r < 4; ++r) {
                unsigned short bv = f2bf(ovv[mf][nf][r]);
                unsigned o = __shfl_xor((unsigned)bv, 1);
                if (!(lane & 1)) {
                    int row = m0 + wv * 32 + mf * 16 + lg * 4 + r;
                    int col = h * 64 + nf * 16 + lr;
                    *reinterpret_cast<unsigned*>(aout + ((size_t)b * TVn + row) * Cn + col) =
                        (unsigned)bv | (o << 16);
                }
            }
}

extern "C" void kernel_launch(void* const* d_in, const int* in_sizes, int n_in,
                              void* d_out, int out_size, void* d_ws, size_t ws_size,
                              hipStream_t stream) {
    const float* video = (const float*)d_in[0];
    const float* text  = (const float*)d_in[1];
    const float* Wq = (const float*)d_in[2];
    const float* Wk = (const float*)d_in[3];
    const float* Wv = (const float*)d_in[4];
    const float* Wo = (const float*)d_in[5];
    float* out = (float*)d_out;

    char* ws = (char*)d_ws;
    unsigned short* wq_b  = (unsigned short*)(ws);                   // 2 MiB
    unsigned short* wo_b  = (unsigned short*)(ws + (2u << 20));      // 2 MiB
    unsigned short* kbuf  = (unsigned short*)(ws + (4u << 20));      // 616 KiB
    unsigned short* vbuf  = (unsigned short*)(ws + (5u << 20));      // 616 KiB
    unsigned short* qhbuf = (unsigned short*)(ws + (6u << 20));      // 64 MiB head-major q
    unsigned short* abuf  = (unsigned short*)(ws + (70u << 20));     // 64 MiB attn out bf16

    // prep: kv-gemm (48 blocks, pipelined) + Wq cvt (512) + Wo cvt (512)
    k_prep<<<48 + 512 + 512, 256, 0, stream>>>(
        text, Wq, Wk, Wv, Wo, wq_b, wo_b, kbuf, vbuf);

    // q = video(fp32, fused cvt) @ Wq^T, written head-major qh[h][b*Tv+row][64]
    k_gq_fused<<<512, 512, 0, stream>>>(video, wq_b, qhbuf);

    // attention: reads qh coalesced; writes row-major into abuf
    dim3 ga(TVn / 256, Hn, Bn);  // 32 x 16 x 4
    k_attn5<<<ga, 512, 0, stream>>>(qhbuf, kbuf, vbuf, abuf);

    // out = attn @ Wo^T (fp32)
    k_g256p8<0><<<512, 512, 0, stream>>>(abuf, wo_b, (void*)out);
}

// Round 18
// 255.498 us; speedup vs baseline: 2.0231x; 2.0231x over previous
//
#include <hip/hip_runtime.h>
#include <hip/hip_bf16.h>

// CrossAttention: B=4, Tv=8192, Tt=77, C=1024, H=16, D=64
// Round 17: exact revert to round-15 config (measured 255.2us best).
// R16's fused q-GEMM spilled its reg banks to scratch (WRITE_SIZE 530MB) -> reverted.

typedef __attribute__((ext_vector_type(8))) short bf16x8;
typedef __attribute__((ext_vector_type(4))) float f32x4;
typedef __attribute__((ext_vector_type(8))) unsigned short u16x8;
typedef __attribute__((ext_vector_type(4))) unsigned short u16x4;

typedef const __attribute__((address_space(1))) void gv_t;
typedef __attribute__((address_space(3))) void lv_t;

static __device__ __forceinline__ unsigned short f2bf(float f) {
    union { float f; unsigned u; } v; v.f = f;
    unsigned r = v.u + 0x7FFFu + ((v.u >> 16) & 1u);  // RNE
    return (unsigned short)(r >> 16);
}

constexpr int Bn = 4, TVn = 8192, TTn = 77, Cn = 1024, Hn = 16;

// ---------------- merged prep: kv-gemm (48 blocks, first) + Wq/Wo cvt + video cvt ----------------
__device__ __forceinline__ void cvt8_body(const float* __restrict__ in,
                                          unsigned short* __restrict__ out, int i) {
    const float4* p = reinterpret_cast<const float4*>(in) + (size_t)i * 2;
    float4 a = p[0], b = p[1];
    u16x8 o = { f2bf(a.x), f2bf(a.y), f2bf(a.z), f2bf(a.w),
                f2bf(b.x), f2bf(b.y), f2bf(b.z), f2bf(b.w) };
    *reinterpret_cast<u16x8*>(out + (size_t)i * 8) = o;
}

__global__ __launch_bounds__(256)
void k_prep(const float* __restrict__ video, const float* __restrict__ text,
            const float* __restrict__ Wq, const float* __restrict__ Wk,
            const float* __restrict__ Wv, const float* __restrict__ Wo,
            unsigned short* __restrict__ wq_b, unsigned short* __restrict__ wo_b,
            unsigned short* __restrict__ kbuf, unsigned short* __restrict__ vbuf,
            unsigned short* __restrict__ vid_b) {
    __shared__ unsigned short As[128 * 32];
    __shared__ unsigned short Bs[128 * 32];
    const int tid = threadIdx.x;
    int bid = blockIdx.x;

    if (bid >= 48) {                                   // conversion blocks
        bid -= 48;
        if (bid < 512)       cvt8_body(Wq, wq_b, bid * 256 + tid);
        else if (bid < 1024) cvt8_body(Wo, wo_b, (bid - 512) * 256 + tid);
        else                 cvt8_body(video, vid_b, (bid - 1024) * 256 + tid);
        return;
    }
    // ---- kv projection: text fp32 [308][1024] @ W^T -> bf16, reg-double-buffered staging
    const int bx = bid % 3, by = (bid / 3) % 8, bz = bid / 24;
    const float* W = bz ? Wv : Wk;
    unsigned short* out = bz ? vbuf : kbuf;
    const int M = Bn * TTn;
    const int lane = tid & 63, wv = tid >> 6;
    const int m0 = bx * 128, n0 = by * 128;
    const int wr = (wv >> 1) * 64, wc = (wv & 1) * 64;
    const int lr = lane & 15, lk = (lane >> 4) * 8, lg = lane >> 4;
    const int srow = tid >> 3, sc4 = (tid & 7) * 4;    // per-thread staging slot (row, col4)
    f32x4 acc[4][4] = {};

    float4 a0[4], b0[4], a1[4], b1[4];                 // two named reg banks (static indexing)

#define KV_LOAD(kk, ra, rb)                                                            \
    {                                                                                  \
        _Pragma("unroll")                                                              \
        for (int it = 0; it < 4; ++it) {                                               \
            int row = it * 32 + srow;                                                  \
            int gr = m0 + row;                                                         \
            ra[it] = make_float4(0.f, 0.f, 0.f, 0.f);                                  \
            if (gr < M) ra[it] = *reinterpret_cast<const float4*>(                     \
                text + (size_t)gr * 1024 + (kk) + sc4);                                \
            rb[it] = *reinterpret_cast<const float4*>(                                 \
                W + (size_t)(n0 + row) * 1024 + (kk) + sc4);                           \
        }                                                                              \
    }

#define KV_WRITE(ra, rb)                                                               \
    {                                                                                  \
        _Pragma("unroll")                                                              \
        for (int it = 0; it < 4; ++it) {                                               \
            int row = it * 32 + srow;                                                  \
            u16x4 oa = { f2bf(ra[it].x), f2bf(ra[it].y), f2bf(ra[it].z), f2bf(ra[it].w) }; \
            *reinterpret_cast<u16x4*>(&As[row * 32 + sc4]) = oa;                       \
            u16x4 ob = { f2bf(rb[it].x), f2bf(rb[it].y), f2bf(rb[it].z), f2bf(rb[it].w) }; \
            *reinterpret_cast<u16x4*>(&Bs[row * 32 + sc4]) = ob;                       \
        }                                                                              \
    }

#define KV_COMPUTE()                                                                   \
    {                                                                                  \
        bf16x8 af[4], bfv[4];                                                          \
        _Pragma("unroll")                                                              \
        for (int m = 0; m < 4; ++m)                                                    \
            af[m] = *reinterpret_cast<const bf16x8*>(&As[(wr + m * 16 + lr) * 32 + lk]); \
        _Pragma("unroll")                                                              \
        for (int n = 0; n < 4; ++n)                                                    \
            bfv[n] = *reinterpret_cast<const bf16x8*>(&Bs[(wc + n * 16 + lr) * 32 + lk]); \
        _Pragma("unroll")                                                              \
        for (int m = 0; m < 4; ++m)                                                    \
            _Pragma("unroll")                                                          \
            for (int n = 0; n < 4; ++n)                                                \
                acc[m][n] = __builtin_amdgcn_mfma_f32_16x16x32_bf16(af[m], bfv[n], acc[m][n], 0, 0, 0); \
    }

    KV_LOAD(0, a0, b0);
    for (int kk = 0; kk < 1024; kk += 64) {
        __syncthreads();                       // previous round's readers done
        KV_WRITE(a0, b0);
        if (kk + 32 < 1024) KV_LOAD(kk + 32, a1, b1);
        __syncthreads();                       // staging visible
        KV_COMPUTE();                          // consumes [kk, kk+32)
        __syncthreads();
        KV_WRITE(a1, b1);
        if (kk + 64 < 1024) KV_LOAD(kk + 64, a0, b0);
        __syncthreads();
        KV_COMPUTE();                          // consumes [kk+32, kk+64)
    }
#undef KV_LOAD
#undef KV_WRITE
#undef KV_COMPUTE

    #pragma unroll
    for (int m = 0; m < 4; ++m)
        #pragma unroll
        for (int n = 0; n < 4; ++n)
            #pragma unroll
            for (int r = 0; r < 4; ++r) {
                int grow = m0 + wr + m * 16 + lg * 4 + r;
                if (grow < M) {
                    int gcol = n0 + wc + n * 16 + lr;
                    out[(size_t)grow * 1024 + gcol] = f2bf(acc[m][n][r]);
                }
            }
}

// ================= 256x256 8-phase counted-vmcnt GEMM =================
// OUT_MODE: 0 = fp32 row-major, 1 = bf16 row-major, 2 = bf16 head-major qh[h][grow][d]
__device__ __forceinline__ void stage_h(const unsigned short* __restrict__ src, int grow0, int kcol0,
                                        unsigned short* lds, int tid) {
    #pragma unroll
    for (int j = 0; j < 2; ++j) {
        const int row = j * 64 + (tid >> 3);
        const int sseg = (tid & 7) ^ (row & 7);
        const unsigned short* g = src + (size_t)(grow0 + row) * 1024 + kcol0 + sseg * 8;
        unsigned short* d = lds + j * 4096 + (tid >> 6) * 512;   // wave-uniform base; HW adds lane*16B
        __builtin_amdgcn_global_load_lds((gv_t*)g, (lv_t*)d, 16, 0, 0);
    }
}

template<int BUF, int MQ>
__device__ __forceinline__ void p8_loadA(bf16x8 (&af)[4][2],
        const unsigned short (&As)[2][2][128][64], int wm, int lr, int lg) {
    #pragma unroll
    for (int m4 = 0; m4 < 4; ++m4)
        #pragma unroll
        for (int kk = 0; kk < 2; ++kk) {
            const int rl = MQ * 64 + m4 * 16 + lr;
            af[m4][kk] = *reinterpret_cast<const bf16x8*>(
                &As[BUF][wm][rl][((kk * 4 + lg) ^ (rl & 7)) * 8]);
        }
}

template<int BUF, int NQ>
__device__ __forceinline__ void p8_loadB(bf16x8 (&bg)[2][2],
        const unsigned short (&Bs)[2][2][128][64], int wn, int lr, int lg) {
    #pragma unroll
    for (int n2 = 0; n2 < 2; ++n2)
        #pragma unroll
        for (int kk = 0; kk < 2; ++kk) {
            const int nrow = wn * 64 + (NQ * 2 + n2) * 16 + lr;
            bg[n2][kk] = *reinterpret_cast<const bf16x8*>(
                &Bs[BUF][nrow >> 7][nrow & 127][((kk * 4 + lg) ^ (nrow & 7)) * 8]);
        }
}

template<int MQ, int NQ>
__device__ __forceinline__ void p8_mfma(f32x4 (&acc)[8][4],
        const bf16x8 (&af)[4][2], const bf16x8 (&bg)[2][2]) {
    #pragma unroll
    for (int m4 = 0; m4 < 4; ++m4)
        #pragma unroll
        for (int n2 = 0; n2 < 2; ++n2)
            #pragma unroll
            for (int kk = 0; kk < 2; ++kk)
                acc[MQ * 4 + m4][NQ * 2 + n2] = __builtin_amdgcn_mfma_f32_16x16x32_bf16(
                    af[m4][kk], bg[n2][kk], acc[MQ * 4 + m4][NQ * 2 + n2], 0, 0, 0);
}

#define P8_PRE()                                              \
    __builtin_amdgcn_s_barrier();                             \
    __builtin_amdgcn_s_setprio(1);

template<int OUT_MODE>
__global__ __launch_bounds__(512, 1)
void k_g256p8(const unsigned short* __restrict__ A, const unsigned short* __restrict__ Wb,
              void* __restrict__ outp) {
    __shared__ unsigned short As[2][2][128][64];   // 64 KiB
    __shared__ unsigned short Bs[2][2][128][64];   // 64 KiB
    const int tid = threadIdx.x, lane = tid & 63;
    const int wid = tid >> 6, wm = wid >> 2, wn = wid & 3;   // 2M x 4N waves
    const int orig = blockIdx.x;
    const int work = (orig & 7) * 64 + (orig >> 3);           // bijective XCD swizzle (512%8==0)
    const int m0 = (work >> 2) * 256, n0 = (work & 3) * 256;
    const int lr = lane & 15, lg = lane >> 4;

    f32x4 acc[8][4] = {};
    bf16x8 af[4][2], bg0[2][2], bg1[2][2];

    // prologue: tile0 (A+B both halves) + B halves of tile1
    stage_h(A,  m0,       0,  &As[0][0][0][0], tid);
    stage_h(A,  m0 + 128, 0,  &As[0][1][0][0], tid);
    stage_h(Wb, n0,       0,  &Bs[0][0][0][0], tid);
    stage_h(Wb, n0 + 128, 0,  &Bs[0][1][0][0], tid);
    stage_h(Wb, n0,       64, &Bs[1][0][0][0], tid);
    stage_h(Wb, n0 + 128, 64, &Bs[1][1][0][0], tid);
    asm volatile("s_waitcnt vmcnt(4)" ::: "memory");   // tile0's 8 loads landed; B(1) in flight
    __builtin_amdgcn_s_barrier();

    for (int t = 0; t < 16; t += 2) {      // tiles t (buf0), t+1 (buf1)
        const int k1 = (t + 1) * 64;
        const bool s2 = (t + 2) < 16, s3 = (t + 3) < 16;
        // P0: tile t (mq0,nq0); stage A0(t+1)
        p8_loadA<0, 0>(af, As, wm, lr, lg);
        p8_loadB<0, 0>(bg0, Bs, wn, lr, lg);
        stage_h(A, m0, k1, &As[1][0][0][0], tid);
        P8_PRE(); p8_mfma<0, 0>(acc, af, bg0);
        __builtin_amdgcn_s_setprio(0); __builtin_amdgcn_s_barrier();
        // P1: (mq0,nq1); stage A1(t+1)
        p8_loadB<0, 1>(bg1, Bs, wn, lr, lg);
        stage_h(A, m0 + 128, k1, &As[1][1][0][0], tid);
        P8_PRE(); p8_mfma<0, 1>(acc, af, bg1);
        __builtin_amdgcn_s_setprio(0); __builtin_amdgcn_s_barrier();
        // P2: (mq1,nq1); stage B0(t+2)
        p8_loadA<0, 1>(af, As, wm, lr, lg);
        if (s2) stage_h(Wb, n0, k1 + 64, &Bs[0][0][0][0], tid);
        P8_PRE(); p8_mfma<1, 1>(acc, af, bg1);
        __builtin_amdgcn_s_setprio(0); __builtin_amdgcn_s_barrier();
        // P3: (mq1,nq0); stage B1(t+2); counted vmcnt
        if (s2) stage_h(Wb, n0 + 128, k1 + 64, &Bs[0][1][0][0], tid);
        P8_PRE(); p8_mfma<1, 0>(acc, af, bg0);
        __builtin_amdgcn_s_setprio(0);
        if (s2) { asm volatile("s_waitcnt vmcnt(4)" ::: "memory"); }
        else    { asm volatile("s_waitcnt vmcnt(0)" ::: "memory"); }
        __builtin_amdgcn_s_barrier();
        // P4: tile t+1 (buf1), (mq0,nq0); stage A0(t+2)
        p8_loadA<1, 0>(af, As, wm, lr, lg);
        p8_loadB<1, 0>(bg0, Bs, wn, lr, lg);
        if (s2) stage_h(A, m0, k1 + 64, &As[0][0][0][0], tid);
        P8_PRE(); p8_mfma<0, 0>(acc, af, bg0);
        __builtin_amdgcn_s_setprio(0); __builtin_amdgcn_s_barrier();
        // P5: (mq0,nq1); stage A1(t+2)
        p8_loadB<1, 1>(bg1, Bs, wn, lr, lg);
        if (s2) stage_h(A, m0 + 128, k1 + 64, &As[0][1][0][0], tid);
        P8_PRE(); p8_mfma<0, 1>(acc, af, bg1);
        __builtin_amdgcn_s_setprio(0); __builtin_amdgcn_s_barrier();
        // P6: (mq1,nq1); stage B0(t+3)
        p8_loadA<1, 1>(af, As, wm, lr, lg);
        if (s3) stage_h(Wb, n0, k1 + 128, &Bs[1][0][0][0], tid);
        P8_PRE(); p8_mfma<1, 1>(acc, af, bg1);
        __builtin_amdgcn_s_setprio(0); __builtin_amdgcn_s_barrier();
        // P7: (mq1,nq0); stage B1(t+3); counted vmcnt
        if (s3) stage_h(Wb, n0 + 128, k1 + 128, &Bs[1][1][0][0], tid);
        P8_PRE(); p8_mfma<1, 0>(acc, af, bg0);
        __builtin_amdgcn_s_setprio(0);
        if (s3) { asm volatile("s_waitcnt vmcnt(4)" ::: "memory"); }
        else    { asm volatile("s_waitcnt vmcnt(0)" ::: "memory"); }
        __builtin_amdgcn_s_barrier();
    }

    #pragma unroll
    for (int mf = 0; mf < 8; ++mf)
        #pragma unroll
        for (int nf = 0; nf < 4; ++nf)
            #pragma unroll
            for (int r = 0; r < 4; ++r) {
                int grow = m0 + wm * 128 + mf * 16 + lg * 4 + r;
                int gcol = n0 + wn * 64 + nf * 16 + lr;
                if (OUT_MODE == 0) {
                    float v = acc[mf][nf][r];
                    float o = __shfl_xor(v, 1);
                    if (!(lane & 1)) {
                        float* out = (float*)outp;
                        float2 pv; pv.x = v; pv.y = o;
                        *reinterpret_cast<float2*>(out + (size_t)grow * 1024 + gcol) = pv;
                    }
                } else {
                    unsigned short bv = f2bf(acc[mf][nf][r]);
                    unsigned ov = __shfl_xor((unsigned)bv, 1);
                    if (!(lane & 1)) {
                        unsigned short* out = (unsigned short*)outp;
                        size_t off = (OUT_MODE == 1)
                            ? (size_t)grow * 1024 + gcol
                            : ((size_t)(gcol >> 6) * (Bn * TVn) + grow) * 64 + (gcol & 63);
                        *reinterpret_cast<unsigned*>(out + off) = (unsigned)bv | (ov << 16);
                    }
                }
            }
}

// ---------------- attention v5: head-major q reads; 256 rows x 1 head per 512-thread block ------
__global__ __launch_bounds__(512)
void k_attn5(const unsigned short* __restrict__ qh,  // [16][32768][64] bf16
             const unsigned short* __restrict__ kb,  // [308][1024]
             const unsigned short* __restrict__ vb,  // [308][1024]
             unsigned short* __restrict__ aout) {    // [32768][1024] bf16
    constexpr int VP = 104;
    __shared__ unsigned short vt_s[64 * VP];
    const int tid = threadIdx.x, lane = tid & 63, wv = tid >> 6;   // wv 0..7
    const int m0 = blockIdx.x * 256;
    const int h = blockIdx.y, b = blockIdx.z;
    const size_t qhbase = ((size_t)h * (Bn * TVn) + (size_t)b * TVn + m0) * 64;
    const size_t kvbase = (size_t)b * TTn * Cn + h * 64;
    const int lr = lane & 15, lg = lane >> 4;

    for (int li = tid; li < 640; li += 512) {
        int t = li >> 3, sg = li & 7;
        u16x8 v = {0, 0, 0, 0, 0, 0, 0, 0};
        if (t < 77) v = *reinterpret_cast<const u16x8*>(vb + kvbase + (size_t)t * Cn + sg * 8);
        #pragma unroll
        for (int i = 0; i < 8; ++i) vt_s[(sg * 8 + i) * VP + t] = v[i];
    }
    for (int li = tid; li < 1024; li += 512) {
        int d = li >> 4, t = 80 + (li & 15);
        vt_s[d * VP + t] = 0;
    }

    f32x4 sc[2][5] = {};
    #pragma unroll
    for (int ks = 0; ks < 2; ++ks) {
        bf16x8 qa[2], kf[5];
        #pragma unroll
        for (int mf = 0; mf < 2; ++mf)
            qa[mf] = *reinterpret_cast<const bf16x8*>(
                qh + qhbase + (size_t)(wv * 32 + mf * 16 + lr) * 64 + ks * 32 + lg * 8);
        #pragma unroll
        for (int nf = 0; nf < 5; ++nf) {
            int t = nf * 16 + lr; if (t > 76) t = 76;
            kf[nf] = *reinterpret_cast<const bf16x8*>(
                kb + kvbase + (size_t)t * Cn + ks * 32 + lg * 8);
        }
        #pragma unroll
        for (int mf = 0; mf < 2; ++mf)
            #pragma unroll
            for (int nf = 0; nf < 5; ++nf)
                sc[mf][nf] = __builtin_amdgcn_mfma_f32_16x16x32_bf16(kf[nf], qa[mf], sc[mf][nf], 0, 0, 0);
    }

    unsigned pk[2][6][2];
    constexpr float CEXP = 0.125f * 1.44269504088896340736f;
    #pragma unroll
    for (int mf = 0; mf < 2; ++mf) {
        float mx = -1e30f;
        #pragma unroll
        for (int nf = 0; nf < 5; ++nf)
            #pragma unroll
            for (int r = 0; r < 4; ++r)
                if (!(nf == 4 && r >= 1)) mx = fmaxf(mx, sc[mf][nf][r]);
                else if (lg != 3)         mx = fmaxf(mx, sc[mf][nf][r]);
        mx = fmaxf(mx, __shfl_xor(mx, 16));
        mx = fmaxf(mx, __shfl_xor(mx, 32));
        float p[5][4];
        float sum = 0.f;
        #pragma unroll
        for (int nf = 0; nf < 5; ++nf)
            #pragma unroll
            for (int r = 0; r < 4; ++r) {
                bool valid = !(nf == 4 && lg == 3 && r >= 1);
                float pv = valid ? exp2f((sc[mf][nf][r] - mx) * CEXP) : 0.f;
                p[nf][r] = pv;
                sum += pv;
            }
        sum += __shfl_xor(sum, 16);
        sum += __shfl_xor(sum, 32);
        float inv = 1.f / sum;
        #pragma unroll
        for (int nf = 0; nf < 5; ++nf) {
            pk[mf][nf][0] = (unsigned)f2bf(p[nf][0] * inv) | ((unsigned)f2bf(p[nf][1] * inv) << 16);
            pk[mf][nf][1] = (unsigned)f2bf(p[nf][2] * inv) | ((unsigned)f2bf(p[nf][3] * inv) << 16);
        }
        pk[mf][5][0] = 0; pk[mf][5][1] = 0;
    }

    __syncthreads();

    f32x4 ovv[2][4] = {};
    const int sel = lg >> 1;
    const int srcA = ((lg & 1) * 2) * 16 + lr;
    const int srcB = ((lg & 1) * 2 + 1) * 16 + lr;
    #pragma unroll
    for (int ks = 0; ks < 3; ++ks) {
        bf16x8 vf[4];
        #pragma unroll
        for (int nf = 0; nf < 4; ++nf)
            vf[nf] = *reinterpret_cast<const bf16x8*>(
                &vt_s[(nf * 16 + lr) * VP + ks * 32 + lg * 8]);
        #pragma unroll
        for (int mf = 0; mf < 2; ++mf) {
            unsigned w0l = __shfl(pk[mf][ks * 2 + 0][0], srcA);
            unsigned w0h = __shfl(pk[mf][ks * 2 + 1][0], srcA);
            unsigned w1l = __shfl(pk[mf][ks * 2 + 0][1], srcA);
            unsigned w1h = __shfl(pk[mf][ks * 2 + 1][1], srcA);
            unsigned w2l = __shfl(pk[mf][ks * 2 + 0][0], srcB);
            unsigned w2h = __shfl(pk[mf][ks * 2 + 1][0], srcB);
            unsigned w3l = __shfl(pk[mf][ks * 2 + 0][1], srcB);
            unsigned w3h = __shfl(pk[mf][ks * 2 + 1][1], srcB);
            union { uint4 u; bf16x8 v; } pa;
            pa.u.x = sel ? w0h : w0l;
            pa.u.y = sel ? w1h : w1l;
            pa.u.z = sel ? w2h : w2l;
            pa.u.w = sel ? w3h : w3l;
            #pragma unroll
            for (int nf = 0; nf < 4; ++nf)
                ovv[mf][nf] = __builtin_amdgcn_mfma_f32_16x16x32_bf16(pa.v, vf[nf], ovv[mf][nf], 0, 0, 0);
        }
    }

    #pragma unroll
    for (int mf = 0; mf < 2; ++mf)
        #pragma unroll
        for (int nf = 0; nf < 4; ++nf)
            #pragma unroll
            for (int r = 0; r < 4; ++r) {
                unsigned short bv = f2bf(ovv[mf][nf][r]);
                unsigned o = __shfl_xor((unsigned)bv, 1);
                if (!(lane & 1)) {
                    int row = m0 + wv * 32 + mf * 16 + lg * 4 + r;
                    int col = h * 64 + nf * 16 + lr;
                    *reinterpret_cast<unsigned*>(aout + ((size_t)b * TVn + row) * Cn + col) =
                        (unsigned)bv | (o << 16);
                }
            }
}

extern "C" void kernel_launch(void* const* d_in, const int* in_sizes, int n_in,
                              void* d_out, int out_size, void* d_ws, size_t ws_size,
                              hipStream_t stream) {
    const float* video = (const float*)d_in[0];
    const float* text  = (const float*)d_in[1];
    const float* Wq = (const float*)d_in[2];
    const float* Wk = (const float*)d_in[3];
    const float* Wv = (const float*)d_in[4];
    const float* Wo = (const float*)d_in[5];
    float* out = (float*)d_out;

    char* ws = (char*)d_ws;
    unsigned short* wq_b  = (unsigned short*)(ws);                   // 2 MiB
    unsigned short* wo_b  = (unsigned short*)(ws + (2u << 20));      // 2 MiB
    unsigned short* kbuf  = (unsigned short*)(ws + (4u << 20));      // 616 KiB
    unsigned short* vbuf  = (unsigned short*)(ws + (5u << 20));      // 616 KiB
    unsigned short* qhbuf = (unsigned short*)(ws + (6u << 20));      // 64 MiB head-major q
    unsigned short* vid_b = (unsigned short*)(ws + (70u << 20));     // 64 MiB video bf16, reused as attn out

    // prep: kv-gemm (48 blocks, pipelined) + Wq cvt (512) + Wo cvt (512) + video cvt (16384)
    k_prep<<<48 + 512 + 512 + 16384, 256, 0, stream>>>(
        video, text, Wq, Wk, Wv, Wo, wq_b, wo_b, kbuf, vbuf, vid_b);

    // q = video @ Wq^T, written head-major qh[h][b*Tv+row][64]
    k_g256p8<2><<<512, 512, 0, stream>>>(vid_b, wq_b, (void*)qhbuf);

    // attention: reads qh coalesced; writes row-major into vid_b (dead)
    dim3 ga(TVn / 256, Hn, Bn);  // 32 x 16 x 4
    k_attn5<<<ga, 512, 0, stream>>>(qhbuf, kbuf, vbuf, vid_b);

    // out = attn @ Wo^T (fp32)
    k_g256p8<0><<<512, 512, 0, stream>>>(vid_b, wo_b, (void*)out);
}

// Round 19
// 253.829 us; speedup vs baseline: 2.0364x; 1.0066x over previous
//
#include <hip/hip_runtime.h>
#include <hip/hip_bf16.h>

// CrossAttention: B=4, Tv=8192, Tt=77, C=1024, H=16, D=64
// Round 18: drop the per-phase PRE barrier in the 8-phase GEMM (one END barrier per
// phase). Each phase's MFMAs consume its ds_reads before the END barrier, so reads
// complete before any re-staging of that region -- wave skew now overlaps LDS+MFMA.

typedef __attribute__((ext_vector_type(8))) short bf16x8;
typedef __attribute__((ext_vector_type(4))) float f32x4;
typedef __attribute__((ext_vector_type(8))) unsigned short u16x8;
typedef __attribute__((ext_vector_type(4))) unsigned short u16x4;

typedef const __attribute__((address_space(1))) void gv_t;
typedef __attribute__((address_space(3))) void lv_t;

static __device__ __forceinline__ unsigned short f2bf(float f) {
    union { float f; unsigned u; } v; v.f = f;
    unsigned r = v.u + 0x7FFFu + ((v.u >> 16) & 1u);  // RNE
    return (unsigned short)(r >> 16);
}

constexpr int Bn = 4, TVn = 8192, TTn = 77, Cn = 1024, Hn = 16;

// ---------------- merged prep: kv-gemm (48 blocks, first) + Wq/Wo cvt + video cvt ----------------
__device__ __forceinline__ void cvt8_body(const float* __restrict__ in,
                                          unsigned short* __restrict__ out, int i) {
    const float4* p = reinterpret_cast<const float4*>(in) + (size_t)i * 2;
    float4 a = p[0], b = p[1];
    u16x8 o = { f2bf(a.x), f2bf(a.y), f2bf(a.z), f2bf(a.w),
                f2bf(b.x), f2bf(b.y), f2bf(b.z), f2bf(b.w) };
    *reinterpret_cast<u16x8*>(out + (size_t)i * 8) = o;
}

__global__ __launch_bounds__(256)
void k_prep(const float* __restrict__ video, const float* __restrict__ text,
            const float* __restrict__ Wq, const float* __restrict__ Wk,
            const float* __restrict__ Wv, const float* __restrict__ Wo,
            unsigned short* __restrict__ wq_b, unsigned short* __restrict__ wo_b,
            unsigned short* __restrict__ kbuf, unsigned short* __restrict__ vbuf,
            unsigned short* __restrict__ vid_b) {
    __shared__ unsigned short As[128 * 32];
    __shared__ unsigned short Bs[128 * 32];
    const int tid = threadIdx.x;
    int bid = blockIdx.x;

    if (bid >= 48) {                                   // conversion blocks
        bid -= 48;
        if (bid < 512)       cvt8_body(Wq, wq_b, bid * 256 + tid);
        else if (bid < 1024) cvt8_body(Wo, wo_b, (bid - 512) * 256 + tid);
        else                 cvt8_body(video, vid_b, (bid - 1024) * 256 + tid);
        return;
    }
    // ---- kv projection: text fp32 [308][1024] @ W^T -> bf16, reg-double-buffered staging
    const int bx = bid % 3, by = (bid / 3) % 8, bz = bid / 24;
    const float* W = bz ? Wv : Wk;
    unsigned short* out = bz ? vbuf : kbuf;
    const int M = Bn * TTn;
    const int lane = tid & 63, wv = tid >> 6;
    const int m0 = bx * 128, n0 = by * 128;
    const int wr = (wv >> 1) * 64, wc = (wv & 1) * 64;
    const int lr = lane & 15, lk = (lane >> 4) * 8, lg = lane >> 4;
    const int srow = tid >> 3, sc4 = (tid & 7) * 4;    // per-thread staging slot (row, col4)
    f32x4 acc[4][4] = {};

    float4 a0[4], b0[4], a1[4], b1[4];                 // two named reg banks (static indexing)

#define KV_LOAD(kk, ra, rb)                                                            \
    {                                                                                  \
        _Pragma("unroll")                                                              \
        for (int it = 0; it < 4; ++it) {                                               \
            int row = it * 32 + srow;                                                  \
            int gr = m0 + row;                                                         \
            ra[it] = make_float4(0.f, 0.f, 0.f, 0.f);                                  \
            if (gr < M) ra[it] = *reinterpret_cast<const float4*>(                     \
                text + (size_t)gr * 1024 + (kk) + sc4);                                \
            rb[it] = *reinterpret_cast<const float4*>(                                 \
                W + (size_t)(n0 + row) * 1024 + (kk) + sc4);                           \
        }                                                                              \
    }

#define KV_WRITE(ra, rb)                                                               \
    {                                                                                  \
        _Pragma("unroll")                                                              \
        for (int it = 0; it < 4; ++it) {                                               \
            int row = it * 32 + srow;                                                  \
            u16x4 oa = { f2bf(ra[it].x), f2bf(ra[it].y), f2bf(ra[it].z), f2bf(ra[it].w) }; \
            *reinterpret_cast<u16x4*>(&As[row * 32 + sc4]) = oa;                       \
            u16x4 ob = { f2bf(rb[it].x), f2bf(rb[it].y), f2bf(rb[it].z), f2bf(rb[it].w) }; \
            *reinterpret_cast<u16x4*>(&Bs[row * 32 + sc4]) = ob;                       \
        }                                                                              \
    }

#define KV_COMPUTE()                                                                   \
    {                                                                                  \
        bf16x8 af[4], bfv[4];                                                          \
        _Pragma("unroll")                                                              \
        for (int m = 0; m < 4; ++m)                                                    \
            af[m] = *reinterpret_cast<const bf16x8*>(&As[(wr + m * 16 + lr) * 32 + lk]); \
        _Pragma("unroll")                                                              \
        for (int n = 0; n < 4; ++n)                                                    \
            bfv[n] = *reinterpret_cast<const bf16x8*>(&Bs[(wc + n * 16 + lr) * 32 + lk]); \
        _Pragma("unroll")                                                              \
        for (int m = 0; m < 4; ++m)                                                    \
            _Pragma("unroll")                                                          \
            for (int n = 0; n < 4; ++n)                                                \
                acc[m][n] = __builtin_amdgcn_mfma_f32_16x16x32_bf16(af[m], bfv[n], acc[m][n], 0, 0, 0); \
    }

    KV_LOAD(0, a0, b0);
    for (int kk = 0; kk < 1024; kk += 64) {
        __syncthreads();                       // previous round's readers done
        KV_WRITE(a0, b0);
        if (kk + 32 < 1024) KV_LOAD(kk + 32, a1, b1);
        __syncthreads();                       // staging visible
        KV_COMPUTE();                          // consumes [kk, kk+32)
        __syncthreads();
        KV_WRITE(a1, b1);
        if (kk + 64 < 1024) KV_LOAD(kk + 64, a0, b0);
        __syncthreads();
        KV_COMPUTE();                          // consumes [kk+32, kk+64)
    }
#undef KV_LOAD
#undef KV_WRITE
#undef KV_COMPUTE

    #pragma unroll
    for (int m = 0; m < 4; ++m)
        #pragma unroll
        for (int n = 0; n < 4; ++n)
            #pragma unroll
            for (int r = 0; r < 4; ++r) {
                int grow = m0 + wr + m * 16 + lg * 4 + r;
                if (grow < M) {
                    int gcol = n0 + wc + n * 16 + lr;
                    out[(size_t)grow * 1024 + gcol] = f2bf(acc[m][n][r]);
                }
            }
}

// ================= 256x256 8-phase counted-vmcnt GEMM (single END barrier per phase) =================
// OUT_MODE: 0 = fp32 row-major, 1 = bf16 row-major, 2 = bf16 head-major qh[h][grow][d]
__device__ __forceinline__ void stage_h(const unsigned short* __restrict__ src, int grow0, int kcol0,
                                        unsigned short* lds, int tid) {
    #pragma unroll
    for (int j = 0; j < 2; ++j) {
        const int row = j * 64 + (tid >> 3);
        const int sseg = (tid & 7) ^ (row & 7);
        const unsigned short* g = src + (size_t)(grow0 + row) * 1024 + kcol0 + sseg * 8;
        unsigned short* d = lds + j * 4096 + (tid >> 6) * 512;   // wave-uniform base; HW adds lane*16B
        __builtin_amdgcn_global_load_lds((gv_t*)g, (lv_t*)d, 16, 0, 0);
    }
}

template<int BUF, int MQ>
__device__ __forceinline__ void p8_loadA(bf16x8 (&af)[4][2],
        const unsigned short (&As)[2][2][128][64], int wm, int lr, int lg) {
    #pragma unroll
    for (int m4 = 0; m4 < 4; ++m4)
        #pragma unroll
        for (int kk = 0; kk < 2; ++kk) {
            const int rl = MQ * 64 + m4 * 16 + lr;
            af[m4][kk] = *reinterpret_cast<const bf16x8*>(
                &As[BUF][wm][rl][((kk * 4 + lg) ^ (rl & 7)) * 8]);
        }
}

template<int BUF, int NQ>
__device__ __forceinline__ void p8_loadB(bf16x8 (&bg)[2][2],
        const unsigned short (&Bs)[2][2][128][64], int wn, int lr, int lg) {
    #pragma unroll
    for (int n2 = 0; n2 < 2; ++n2)
        #pragma unroll
        for (int kk = 0; kk < 2; ++kk) {
            const int nrow = wn * 64 + (NQ * 2 + n2) * 16 + lr;
            bg[n2][kk] = *reinterpret_cast<const bf16x8*>(
                &Bs[BUF][nrow >> 7][nrow & 127][((kk * 4 + lg) ^ (nrow & 7)) * 8]);
        }
}

template<int MQ, int NQ>
__device__ __forceinline__ void p8_mfma(f32x4 (&acc)[8][4],
        const bf16x8 (&af)[4][2], const bf16x8 (&bg)[2][2]) {
    #pragma unroll
    for (int m4 = 0; m4 < 4; ++m4)
        #pragma unroll
        for (int n2 = 0; n2 < 2; ++n2)
            #pragma unroll
            for (int kk = 0; kk < 2; ++kk)
                acc[MQ * 4 + m4][NQ * 2 + n2] = __builtin_amdgcn_mfma_f32_16x16x32_bf16(
                    af[m4][kk], bg[n2][kk], acc[MQ * 4 + m4][NQ * 2 + n2], 0, 0, 0);
}

// Single-barrier phase: MFMAs consume this phase's ds_reads (compiler lgkmcnt) before
// the wave reaches the END barrier, so all reads of a region complete before any wave
// passes the barrier after which that region is re-staged.
#define P8_PRE()  __builtin_amdgcn_s_setprio(1);

template<int OUT_MODE>
__global__ __launch_bounds__(512, 1)
void k_g256p8(const unsigned short* __restrict__ A, const unsigned short* __restrict__ Wb,
              void* __restrict__ outp) {
    __shared__ unsigned short As[2][2][128][64];   // 64 KiB
    __shared__ unsigned short Bs[2][2][128][64];   // 64 KiB
    const int tid = threadIdx.x, lane = tid & 63;
    const int wid = tid >> 6, wm = wid >> 2, wn = wid & 3;   // 2M x 4N waves
    const int orig = blockIdx.x;
    const int work = (orig & 7) * 64 + (orig >> 3);           // bijective XCD swizzle (512%8==0)
    const int m0 = (work >> 2) * 256, n0 = (work & 3) * 256;
    const int lr = lane & 15, lg = lane >> 4;

    f32x4 acc[8][4] = {};
    bf16x8 af[4][2], bg0[2][2], bg1[2][2];

    // prologue: tile0 (A+B both halves) + B halves of tile1
    stage_h(A,  m0,       0,  &As[0][0][0][0], tid);
    stage_h(A,  m0 + 128, 0,  &As[0][1][0][0], tid);
    stage_h(Wb, n0,       0,  &Bs[0][0][0][0], tid);
    stage_h(Wb, n0 + 128, 0,  &Bs[0][1][0][0], tid);
    stage_h(Wb, n0,       64, &Bs[1][0][0][0], tid);
    stage_h(Wb, n0 + 128, 64, &Bs[1][1][0][0], tid);
    asm volatile("s_waitcnt vmcnt(4)" ::: "memory");   // tile0's 8 loads landed; B(1) in flight
    __builtin_amdgcn_s_barrier();

    for (int t = 0; t < 16; t += 2) {      // tiles t (buf0), t+1 (buf1)
        const int k1 = (t + 1) * 64;
        const bool s2 = (t + 2) < 16, s3 = (t + 3) < 16;
        // P0: tile t (mq0,nq0); stage A0(t+1)
        p8_loadA<0, 0>(af, As, wm, lr, lg);
        p8_loadB<0, 0>(bg0, Bs, wn, lr, lg);
        stage_h(A, m0, k1, &As[1][0][0][0], tid);
        P8_PRE(); p8_mfma<0, 0>(acc, af, bg0);
        __builtin_amdgcn_s_setprio(0); __builtin_amdgcn_s_barrier();
        // P1: (mq0,nq1); stage A1(t+1)
        p8_loadB<0, 1>(bg1, Bs, wn, lr, lg);
        stage_h(A, m0 + 128, k1, &As[1][1][0][0], tid);
        P8_PRE(); p8_mfma<0, 1>(acc, af, bg1);
        __builtin_amdgcn_s_setprio(0); __builtin_amdgcn_s_barrier();
        // P2: (mq1,nq1); stage B0(t+2)
        p8_loadA<0, 1>(af, As, wm, lr, lg);
        if (s2) stage_h(Wb, n0, k1 + 64, &Bs[0][0][0][0], tid);
        P8_PRE(); p8_mfma<1, 1>(acc, af, bg1);
        __builtin_amdgcn_s_setprio(0); __builtin_amdgcn_s_barrier();
        // P3: (mq1,nq0); stage B1(t+2); counted vmcnt
        if (s2) stage_h(Wb, n0 + 128, k1 + 64, &Bs[0][1][0][0], tid);
        P8_PRE(); p8_mfma<1, 0>(acc, af, bg0);
        __builtin_amdgcn_s_setprio(0);
        if (s2) { asm volatile("s_waitcnt vmcnt(4)" ::: "memory"); }
        else    { asm volatile("s_waitcnt vmcnt(0)" ::: "memory"); }
        __builtin_amdgcn_s_barrier();
        // P4: tile t+1 (buf1), (mq0,nq0); stage A0(t+2)
        p8_loadA<1, 0>(af, As, wm, lr, lg);
        p8_loadB<1, 0>(bg0, Bs, wn, lr, lg);
        if (s2) stage_h(A, m0, k1 + 64, &As[0][0][0][0], tid);
        P8_PRE(); p8_mfma<0, 0>(acc, af, bg0);
        __builtin_amdgcn_s_setprio(0); __builtin_amdgcn_s_barrier();
        // P5: (mq0,nq1); stage A1(t+2)
        p8_loadB<1, 1>(bg1, Bs, wn, lr, lg);
        if (s2) stage_h(A, m0 + 128, k1 + 64, &As[0][1][0][0], tid);
        P8_PRE(); p8_mfma<0, 1>(acc, af, bg1);
        __builtin_amdgcn_s_setprio(0); __builtin_amdgcn_s_barrier();
        // P6: (mq1,nq1); stage B0(t+3)
        p8_loadA<1, 1>(af, As, wm, lr, lg);
        if (s3) stage_h(Wb, n0, k1 + 128, &Bs[1][0][0][0], tid);
        P8_PRE(); p8_mfma<1, 1>(acc, af, bg1);
        __builtin_amdgcn_s_setprio(0); __builtin_amdgcn_s_barrier();
        // P7: (mq1,nq0); stage B1(t+3); counted vmcnt
        if (s3) stage_h(Wb, n0 + 128, k1 + 128, &Bs[1][1][0][0], tid);
        P8_PRE(); p8_mfma<1, 0>(acc, af, bg0);
        __builtin_amdgcn_s_setprio(0);
        if (s3) { asm volatile("s_waitcnt vmcnt(4)" ::: "memory"); }
        else    { asm volatile("s_waitcnt vmcnt(0)" ::: "memory"); }
        __builtin_amdgcn_s_barrier();
    }

    #pragma unroll
    for (int mf = 0; mf < 8; ++mf)
        #pragma unroll
        for (int nf = 0; nf < 4; ++nf)
            #pragma unroll
            for (int r = 0; r < 4; ++r) {
                int grow = m0 + wm * 128 + mf * 16 + lg * 4 + r;
                int gcol = n0 + wn * 64 + nf * 16 + lr;
                if (OUT_MODE == 0) {
                    float v = acc[mf][nf][r];
                    float o = __shfl_xor(v, 1);
                    if (!(lane & 1)) {
                        float* out = (float*)outp;
                        float2 pv; pv.x = v; pv.y = o;
                        *reinterpret_cast<float2*>(out + (size_t)grow * 1024 + gcol) = pv;
                    }
                } else {
                    unsigned short bv = f2bf(acc[mf][nf][r]);
                    unsigned ov = __shfl_xor((unsigned)bv, 1);
                    if (!(lane & 1)) {
                        unsigned short* out = (unsigned short*)outp;
                        size_t off = (OUT_MODE == 1)
                            ? (size_t)grow * 1024 + gcol
                            : ((size_t)(gcol >> 6) * (Bn * TVn) + grow) * 64 + (gcol & 63);
                        *reinterpret_cast<unsigned*>(out + off) = (unsigned)bv | (ov << 16);
                    }
                }
            }
}

// ---------------- attention v5: head-major q reads; 256 rows x 1 head per 512-thread block ------
__global__ __launch_bounds__(512)
void k_attn5(const unsigned short* __restrict__ qh,  // [16][32768][64] bf16
             const unsigned short* __restrict__ kb,  // [308][1024]
             const unsigned short* __restrict__ vb,  // [308][1024]
             unsigned short* __restrict__ aout) {    // [32768][1024] bf16
    constexpr int VP = 104;
    __shared__ unsigned short vt_s[64 * VP];
    const int tid = threadIdx.x, lane = tid & 63, wv = tid >> 6;   // wv 0..7
    const int m0 = blockIdx.x * 256;
    const int h = blockIdx.y, b = blockIdx.z;
    const size_t qhbase = ((size_t)h * (Bn * TVn) + (size_t)b * TVn + m0) * 64;
    const size_t kvbase = (size_t)b * TTn * Cn + h * 64;
    const int lr = lane & 15, lg = lane >> 4;

    for (int li = tid; li < 640; li += 512) {
        int t = li >> 3, sg = li & 7;
        u16x8 v = {0, 0, 0, 0, 0, 0, 0, 0};
        if (t < 77) v = *reinterpret_cast<const u16x8*>(vb + kvbase + (size_t)t * Cn + sg * 8);
        #pragma unroll
        for (int i = 0; i < 8; ++i) vt_s[(sg * 8 + i) * VP + t] = v[i];
    }
    for (int li = tid; li < 1024; li += 512) {
        int d = li >> 4, t = 80 + (li & 15);
        vt_s[d * VP + t] = 0;
    }

    f32x4 sc[2][5] = {};
    #pragma unroll
    for (int ks = 0; ks < 2; ++ks) {
        bf16x8 qa[2], kf[5];
        #pragma unroll
        for (int mf = 0; mf < 2; ++mf)
            qa[mf] = *reinterpret_cast<const bf16x8*>(
                qh + qhbase + (size_t)(wv * 32 + mf * 16 + lr) * 64 + ks * 32 + lg * 8);
        #pragma unroll
        for (int nf = 0; nf < 5; ++nf) {
            int t = nf * 16 + lr; if (t > 76) t = 76;
            kf[nf] = *reinterpret_cast<const bf16x8*>(
                kb + kvbase + (size_t)t * Cn + ks * 32 + lg * 8);
        }
        #pragma unroll
        for (int mf = 0; mf < 2; ++mf)
            #pragma unroll
            for (int nf = 0; nf < 5; ++nf)
                sc[mf][nf] = __builtin_amdgcn_mfma_f32_16x16x32_bf16(kf[nf], qa[mf], sc[mf][nf], 0, 0, 0);
    }

    unsigned pk[2][6][2];
    constexpr float CEXP = 0.125f * 1.44269504088896340736f;
    #pragma unroll
    for (int mf = 0; mf < 2; ++mf) {
        float mx = -1e30f;
        #pragma unroll
        for (int nf = 0; nf < 5; ++nf)
            #pragma unroll
            for (int r = 0; r < 4; ++r)
                if (!(nf == 4 && r >= 1)) mx = fmaxf(mx, sc[mf][nf][r]);
                else if (lg != 3)         mx = fmaxf(mx, sc[mf][nf][r]);
        mx = fmaxf(mx, __shfl_xor(mx, 16));
        mx = fmaxf(mx, __shfl_xor(mx, 32));
        float p[5][4];
        float sum = 0.f;
        #pragma unroll
        for (int nf = 0; nf < 5; ++nf)
            #pragma unroll
            for (int r = 0; r < 4; ++r) {
                bool valid = !(nf == 4 && lg == 3 && r >= 1);
                float pv = valid ? exp2f((sc[mf][nf][r] - mx) * CEXP) : 0.f;
                p[nf][r] = pv;
                sum += pv;
            }
        sum += __shfl_xor(sum, 16);
        sum += __shfl_xor(sum, 32);
        float inv = 1.f / sum;
        #pragma unroll
        for (int nf = 0; nf < 5; ++nf) {
            pk[mf][nf][0] = (unsigned)f2bf(p[nf][0] * inv) | ((unsigned)f2bf(p[nf][1] * inv) << 16);
            pk[mf][nf][1] = (unsigned)f2bf(p[nf][2] * inv) | ((unsigned)f2bf(p[nf][3] * inv) << 16);
        }
        pk[mf][5][0] = 0; pk[mf][5][1] = 0;
    }

    __syncthreads();

    f32x4 ovv[2][4] = {};
    const int sel = lg >> 1;
    const int srcA = ((lg & 1) * 2) * 16 + lr;
    const int srcB = ((lg & 1) * 2 + 1) * 16 + lr;
    #pragma unroll
    for (int ks = 0; ks < 3; ++ks) {
        bf16x8 vf[4];
        #pragma unroll
        for (int nf = 0; nf < 4; ++nf)
            vf[nf] = *reinterpret_cast<const bf16x8*>(
                &vt_s[(nf * 16 + lr) * VP + ks * 32 + lg * 8]);
        #pragma unroll
        for (int mf = 0; mf < 2; ++mf) {
            unsigned w0l = __shfl(pk[mf][ks * 2 + 0][0], srcA);
            unsigned w0h = __shfl(pk[mf][ks * 2 + 1][0], srcA);
            unsigned w1l = __shfl(pk[mf][ks * 2 + 0][1], srcA);
            unsigned w1h = __shfl(pk[mf][ks * 2 + 1][1], srcA);
            unsigned w2l = __shfl(pk[mf][ks * 2 + 0][0], srcB);
            unsigned w2h = __shfl(pk[mf][ks * 2 + 1][0], srcB);
            unsigned w3l = __shfl(pk[mf][ks * 2 + 0][1], srcB);
            unsigned w3h = __shfl(pk[mf][ks * 2 + 1][1], srcB);
            union { uint4 u; bf16x8 v; } pa;
            pa.u.x = sel ? w0h : w0l;
            pa.u.y = sel ? w1h : w1l;
            pa.u.z = sel ? w2h : w2l;
            pa.u.w = sel ? w3h : w3l;
            #pragma unroll
            for (int nf = 0; nf < 4; ++nf)
                ovv[mf][nf] = __builtin_amdgcn_mfma_f32_16x16x32_bf16(pa.v, vf[nf], ovv[mf][nf], 0, 0, 0);
        }
    }

    #pragma unroll
    for (int mf = 0; mf < 2; ++mf)
        #pragma unroll
        for (int nf = 0; nf < 4; ++nf)
            #pragma unroll
            for (int r = 0; r < 4; ++r) {
                unsigned short bv = f2bf(ovv[mf][nf][r]);
                unsigned o = __shfl_xor((unsigned)bv, 1);
                if (!(lane & 1)) {
                    int row = m0 + wv * 32 + mf * 16 + lg * 4 + r;
                    int col = h * 64 + nf * 16 + lr;
                    *reinterpret_cast<unsigned*>(aout + ((size_t)b * TVn + row) * Cn + col) =
                        (unsigned)bv | (o << 16);
                }
            }
}

extern "C" void kernel_launch(void* const* d_in, const int* in_sizes, int n_in,
                              void* d_out, int out_size, void* d_ws, size_t ws_size,
                              hipStream_t stream) {
    const float* video = (const float*)d_in[0];
    const float* text  = (const float*)d_in[1];
    const float* Wq = (const float*)d_in[2];
    const float* Wk = (const float*)d_in[3];
    const float* Wv = (const float*)d_in[4];
    const float* Wo = (const float*)d_in[5];
    float* out = (float*)d_out;

    char* ws = (char*)d_ws;
    unsigned short* wq_b  = (unsigned short*)(ws);                   // 2 MiB
    unsigned short* wo_b  = (unsigned short*)(ws + (2u << 20));      // 2 MiB
    unsigned short* kbuf  = (unsigned short*)(ws + (4u << 20));      // 616 KiB
    unsigned short* vbuf  = (unsigned short*)(ws + (5u << 20));      // 616 KiB
    unsigned short* qhbuf = (unsigned short*)(ws + (6u << 20));      // 64 MiB head-major q
    unsigned short* vid_b = (unsigned short*)(ws + (70u << 20));     // 64 MiB video bf16, reused as attn out

    // prep: kv-gemm (48 blocks, pipelined) + Wq cvt (512) + Wo cvt (512) + video cvt (16384)
    k_prep<<<48 + 512 + 512 + 16384, 256, 0, stream>>>(
        video, text, Wq, Wk, Wv, Wo, wq_b, wo_b, kbuf, vbuf, vid_b);

    // q = video @ Wq^T, written head-major qh[h][b*Tv+row][64]
    k_g256p8<2><<<512, 512, 0, stream>>>(vid_b, wq_b, (void*)qhbuf);

    // attention: reads qh coalesced; writes row-major into vid_b (dead)
    dim3 ga(TVn / 256, Hn, Bn);  // 32 x 16 x 4
    k_attn5<<<ga, 512, 0, stream>>>(qhbuf, kbuf, vbuf, vid_b);

    // out = attn @ Wo^T (fp32)
    k_g256p8<0><<<512, 512, 0, stream>>>(vid_b, wo_b, (void*)out);
}